// Round 8
// baseline (149.992 us; speedup 1.0000x reference)
//
#include <hip/hip_runtime.h>

#define BB 2048
#define DD 4096
#define PP 64
#define KK 64
#define EE 8
#define C2 128
#define NBLK BB        // 1 row per block; 4 waves = 4 channel-quarters (2 nt each)
#define NGRP 32        // loss-accumulator copies (contention spreading)
#define GRPSZ (NBLK / NGRP)   // 64 blocks per copy -> max same-address atomic chain = 64

typedef __attribute__((ext_vector_type(8))) short short8;
typedef __attribute__((ext_vector_type(4))) float floatx4;

// Fused loss, hierarchical + init-free across iterations/graph-replays:
//  - R6 lesson: ~20K device-scope RMWs on ONE cacheline serialize at ~14 cyc each (~120 us).
//    Spread over 32 copies (64 blocks each) -> max chain 64 RMWs (~0.4 us).
//  - counters are monotone; per-iteration detection via mod (c1[g] += 1 per block, 64/iter;
//    c2 += 1 per group-last, 32/iter). No zeroing dispatch needed.
//  - g_sum zeroed at module load; finalizer resets it after reading; kernel-boundary ordering
//    publishes the reset to the next iteration. Ordering chain: g_sum adds -> release c1[g]
//    -> group-last (acq_rel) -> release c2 -> finalizer (acq_rel) => all adds visible.
__device__ float    g_sum[NGRP][16] = {};
__device__ unsigned g_c1[NGRP] = {};
__device__ unsigned g_c2 = 0u;

__device__ inline unsigned pack2_trunc(float lo, float hi) { // 2 bf16 (truncate) in 1 u32
    unsigned ul = __builtin_bit_cast(unsigned, lo);
    unsigned uh = __builtin_bit_cast(unsigned, hi);
    return (uh & 0xFFFF0000u) | (ul >> 16);
}

// async global->LDS, 16B per lane, zero VGPR destination cost.
// LDS dest = wave-uniform base + lane*16 (HW semantic); global src is per-lane.
__device__ inline void gload16(const float* src, float* lds_dst_uniform) {
    __builtin_amdgcn_global_load_lds(
        (const __attribute__((address_space(1))) unsigned int*)src,
        (__attribute__((address_space(3))) unsigned int*)lds_dst_uniform, 16, 0, 0);
}

// One row per BLOCK, 4 waves each owning 32 output channels (nt = 2w, 2w+1).
// x staged via global_load_lds (16 KB row, zero-VGPR fetch, XOR-swizzled src + swizzled read).
// Router run redundantly per wave (bit-identical => same e/gate, no sync needed).
// Loss fused via hierarchical atomics (see above): ONE launch total beside the harness fill.
__global__ __launch_bounds__(256) void moe_main(
    const float* __restrict__ x, const float* __restrict__ rw,
    const float* __restrict__ ew, const float* __restrict__ eb,
    float* __restrict__ out)
{
    __shared__ float xs[64 * 64];                        // 16 KB: x row, [patch][k], swizzled
    __shared__ float sh_h[4];                            // per-wave channel-quarter sums
    const int lane = threadIdx.x & 63;
    const int w = threadIdx.x >> 6;
    const int b = blockIdx.x;
    const int r = lane & 15, q = lane >> 4;
    const float* xb = x + (size_t)b * DD;

    // ---- stage x row into LDS (16 x 1KB issues, 4 per wave), swizzled at the source:
    // LDS[row][G] = global[row][G ^ (row&7)]  (G = 16B granule index 0..15 within a row)
    #pragma unroll
    for (int j = 0; j < 4; ++j) {
        const int row = (w * 4 + j) * 4 + (lane >> 4);   // this lane's global row
        const int g   = (lane & 15) ^ (row & 7);         // pre-swizzled source granule
        gload16(xb + row * 64 + g * 4, &xs[(w * 4 + j) * 256]);  // dst uniform per wave
    }
    __syncthreads();                                     // compiler drains vmcnt(0) before barrier

    // ---- read x from LDS in MFMA A-layout; fp32 col-sum partials; pack bf16 A-frags
    const int s = r & 7;                                 // read-side XOR key: (mt*16+r)&7 == r&7
    float ps[16];
    #pragma unroll
    for (int j = 0; j < 16; ++j) ps[j] = 0.f;
    short8 af[8];                                        // [mt*2+kb]
    #pragma unroll
    for (int mt = 0; mt < 4; ++mt) {
        #pragma unroll
        for (int kb = 0; kb < 2; ++kb) {
            const float* base = &xs[(mt * 16 + r) * 64 + kb * 32];
            float4 v0 = *(const float4*)(base + (((q * 2 + 0) ^ s) << 2));
            float4 v1 = *(const float4*)(base + (((q * 2 + 1) ^ s) << 2));
            ps[kb*8+0] += v0.x; ps[kb*8+1] += v0.y; ps[kb*8+2] += v0.z; ps[kb*8+3] += v0.w;
            ps[kb*8+4] += v1.x; ps[kb*8+5] += v1.y; ps[kb*8+6] += v1.z; ps[kb*8+7] += v1.w;
            uint4 u;
            u.x = pack2_trunc(v0.x, v0.y); u.y = pack2_trunc(v0.z, v0.w);
            u.z = pack2_trunc(v1.x, v1.y); u.w = pack2_trunc(v1.z, v1.w);
            af[mt * 2 + kb] = __builtin_bit_cast(short8, u);
        }
    }

    // ---- router (fp32; strict first-max argmax matches np). Redundant across the 4 waves:
    // identical instruction sequence on identical data -> bit-identical d[], e, gate.
    float d[8];
    #pragma unroll
    for (int e2 = 0; e2 < 8; ++e2) {
        const float* rwe = rw + e2 * KK;
        float4 a0 = *(const float4*)(rwe + q * 8);
        float4 a1 = *(const float4*)(rwe + q * 8 + 4);
        float4 b0 = *(const float4*)(rwe + 32 + q * 8);
        float4 b1 = *(const float4*)(rwe + 32 + q * 8 + 4);
        float t = ps[0]*a0.x + ps[1]*a0.y + ps[2]*a0.z + ps[3]*a0.w
                + ps[4]*a1.x + ps[5]*a1.y + ps[6]*a1.z + ps[7]*a1.w
                + ps[8]*b0.x + ps[9]*b0.y + ps[10]*b0.z + ps[11]*b0.w
                + ps[12]*b1.x + ps[13]*b1.y + ps[14]*b1.z + ps[15]*b1.w;
        t += __shfl_xor(t, 1);  t += __shfl_xor(t, 2);  t += __shfl_xor(t, 4);
        t += __shfl_xor(t, 8);  t += __shfl_xor(t, 16); t += __shfl_xor(t, 32);
        d[e2] = t;                                       // all lanes hold it
    }
    float gate = d[0]; int e = 0;
    #pragma unroll
    for (int e2 = 1; e2 < 8; ++e2)
        if (d[e2] > gate) { gate = d[e2]; e = e2; }

    // ---- select0 output straight from registers (wave 0, lanes 0..7)
    if (w == 0 && lane < 8) {
        float on = (gate != 0.f) ? 1.f : 0.f;
        out[BB * 2 + b * 8 + lane] = (lane == e) ? on : 0.f;   // select0 (one-hot row)
    }

    // ---- expert compute (this wave's 32 channels): inline fp32->bf16 B-frags, mfma, (z+bias)^3
    const float* we = ew + (size_t)e * (C2 * KK);
    float h = 0.f;
    #pragma unroll
    for (int ntl = 0; ntl < 2; ++ntl) {
        const int nt = w * 2 + ntl;
        float bs = eb[e * C2 + nt * 16 + r];             // c = nt*16 + (lane&15)
        const float* wr = we + (nt * 16 + r) * KK + q * 8;
        float4 w0 = *(const float4*)wr;
        float4 w1 = *(const float4*)(wr + 4);
        float4 w2 = *(const float4*)(wr + 32);
        float4 w3 = *(const float4*)(wr + 36);
        uint4 u0, u1;
        u0.x = pack2_trunc(w0.x, w0.y); u0.y = pack2_trunc(w0.z, w0.w);
        u0.z = pack2_trunc(w1.x, w1.y); u0.w = pack2_trunc(w1.z, w1.w);
        u1.x = pack2_trunc(w2.x, w2.y); u1.y = pack2_trunc(w2.z, w2.w);
        u1.z = pack2_trunc(w3.x, w3.y); u1.w = pack2_trunc(w3.z, w3.w);
        short8 bf0 = __builtin_bit_cast(short8, u0);
        short8 bf1 = __builtin_bit_cast(short8, u1);
        #pragma unroll
        for (int mt = 0; mt < 4; ++mt) {
            floatx4 a4 = (floatx4){0.f, 0.f, 0.f, 0.f};
            a4 = __builtin_amdgcn_mfma_f32_16x16x32_bf16(af[mt*2+0], bf0, a4, 0, 0, 0);
            a4 = __builtin_amdgcn_mfma_f32_16x16x32_bf16(af[mt*2+1], bf1, a4, 0, 0, 0);
            #pragma unroll
            for (int i = 0; i < 4; ++i) {
                float z = a4[i] + bs;
                h = fmaf(z * z, z, h);
            }
        }
    }
    #pragma unroll
    for (int off = 1; off < 64; off <<= 1)
        h += __shfl_xor(h, off);

    if (lane == 0) sh_h[w] = h;
    __syncthreads();

    if (threadIdx.x == 0) {
        float l0 = gate * (sh_h[0] + sh_h[1]);           // channels 0..63
        float l1 = gate * (sh_h[2] + sh_h[3]);           // channels 64..127
        float m = fmaxf(l0, l1);
        float e0 = __expf(l0 - m), e1 = __expf(l1 - m);
        float inv = 1.f / (e0 + e1);
        float2 o; o.x = e0 * inv; o.y = e1 * inv;
        *(float2*)(out + b * 2) = o;
    }

    // ---- fused loss (wave 0 only, AFTER all outputs; off other blocks' critical path)
    if (w == 0) {
        const int grp = b & (NGRP - 1);
        if (lane < 8) {
            atomicAdd(&g_sum[grp][lane], d[lane]);       // sum_b select[b,e]  (8 adds/block)
            if (lane == e)
                atomicAdd(&g_sum[grp][8 + lane], 1.f);   // argmax count      (1 add/block)
        }
        if (lane == 0) {
            // release: orders this wave's g_sum adds before the counter bump
            unsigned o1 = __hip_atomic_fetch_add(&g_c1[grp], 1u,
                                                 __ATOMIC_ACQ_REL, __HIP_MEMORY_SCOPE_AGENT);
            if ((o1 % GRPSZ) == GRPSZ - 1u) {            // last block of this copy, this iter
                unsigned o2 = __hip_atomic_fetch_add(&g_c2, 1u,
                                                     __ATOMIC_ACQ_REL, __HIP_MEMORY_SCOPE_AGENT);
                if ((o2 % NGRP) == NGRP - 1u) {          // last group -> all 2048 blocks' adds visible
                    float sp[8], sc[8];
                    #pragma unroll
                    for (int j = 0; j < 8; ++j) { sp[j] = 0.f; sc[j] = 0.f; }
                    for (int g2 = 0; g2 < NGRP; ++g2) {  // 512 independent L2 atomic loads, pipelined
                        #pragma unroll
                        for (int j = 0; j < 8; ++j) {
                            sp[j] += __hip_atomic_load(&g_sum[g2][j],     __ATOMIC_RELAXED, __HIP_MEMORY_SCOPE_AGENT);
                            sc[j] += __hip_atomic_load(&g_sum[g2][8 + j], __ATOMIC_RELAXED, __HIP_MEMORY_SCOPE_AGENT);
                        }
                    }
                    float loss = 0.f;
                    #pragma unroll
                    for (int j = 0; j < 8; ++j)
                        loss += (sp[j] * (1.f / BB)) * (sc[j] * (1.f / BB));
                    out[BB * 2 + BB * 8] = loss * (float)EE;
                    for (int g2 = 0; g2 < NGRP; ++g2)    // reset for next iteration (published by
                        #pragma unroll                   // the kernel boundary)
                        for (int j = 0; j < 16; ++j)
                            __hip_atomic_store(&g_sum[g2][j], 0.f,
                                               __ATOMIC_RELAXED, __HIP_MEMORY_SCOPE_AGENT);
                }
            }
        }
    }
}

extern "C" void kernel_launch(void* const* d_in, const int* in_sizes, int n_in,
                              void* d_out, int out_size, void* d_ws, size_t ws_size,
                              hipStream_t stream) {
    (void)in_sizes; (void)n_in; (void)out_size; (void)d_ws; (void)ws_size;
    const float* x  = (const float*)d_in[0];
    const float* rw = (const float*)d_in[1];
    const float* ew = (const float*)d_in[2];
    const float* eb = (const float*)d_in[3];
    float* out = (float*)d_out;

    moe_main<<<NBLK, 256, 0, stream>>>(x, rw, ew, eb, out);
}

// Round 9
// 97.486 us; speedup vs baseline: 1.5386x; 1.5386x over previous
//
#include <hip/hip_runtime.h>

#define BB 2048
#define DD 4096
#define PP 64
#define KK 64
#define EE 8
#define C2 128
#define NBLK BB        // 1 row per block; 4 waves: stage/route own mt-quarter, compute 32 channels
#define NGRP 32        // loss-accumulator copies (spread RELAXED adds; R8: ordered RMWs cost ~30ns ea)

typedef __attribute__((ext_vector_type(8))) short short8;
typedef __attribute__((ext_vector_type(4))) float floatx4;

// Loss accumulators: RELAXED atomicAdds only (R1 evidence: cheap; R6/R8: acq-rel agent-scope
// RMWs serialize ~30-70ns each chip-wide -> never per-block). Zero at module load; loss2
// resets after reading; kernel-boundary ordering publishes adds -> loss2 and reset -> next iter.
__device__ float g_sum[NGRP][16] = {};

__device__ inline unsigned pack2_trunc(float lo, float hi) { // 2 bf16 (truncate) in 1 u32
    unsigned ul = __builtin_bit_cast(unsigned, lo);
    unsigned uh = __builtin_bit_cast(unsigned, hi);
    return (uh & 0xFFFF0000u) | (ul >> 16);
}

// async global->LDS, 16B per lane, zero VGPR destination cost.
// LDS dest = wave-uniform base + lane*16 (HW semantic); global src is per-lane.
__device__ inline void gload16(const float* src, float* lds_dst_uniform) {
    __builtin_amdgcn_global_load_lds(
        (const __attribute__((address_space(1))) unsigned int*)src,
        (__attribute__((address_space(3))) unsigned int*)lds_dst_uniform, 16, 0, 0);
}

// One row per BLOCK. Pipelined routing: wave w stages ONLY rows [16w,16w+16) (4 KB), waits
// per-wave vmcnt(0) (no barrier), computes its quarter's router partial d_w[8] (butterfly over
// its 16 patches x full K), publishes 8 floats to LDS. The single barrier then guarantees both
// "all x staged" and "all partials visible". Waves merge d in fixed order (bit-identical),
// argmax, then expert-weight loads overlap the full-row A-frag ds_reads. Critical path no
// longer contains {full 16KB stage-wait -> full router} before the data-dependent weight load.
__global__ __launch_bounds__(256) void moe_main(
    const float* __restrict__ x, const float* __restrict__ rw,
    const float* __restrict__ ew, const float* __restrict__ eb,
    float* __restrict__ out)
{
    __shared__ float xs[64 * 64];                        // 16 KB: x row, [patch][k], swizzled
    __shared__ float sh_d[4][8];                         // per-wave router partials
    __shared__ float sh_h[4];                            // per-wave channel-quarter sums
    const int lane = threadIdx.x & 63;
    const int w = threadIdx.x >> 6;
    const int b = blockIdx.x;
    const int r = lane & 15, q = lane >> 4;
    const float* xb = x + (size_t)b * DD;

    // ---- stage OWN quarter (rows 16w..16w+15), swizzled at the source:
    // LDS[row][G] = global[row][G ^ (row&7)]  (G = 16B granule index 0..15 within a row)
    #pragma unroll
    for (int j = 0; j < 4; ++j) {
        const int row = w * 16 + j * 4 + (lane >> 4);
        const int g   = (lane & 15) ^ (row & 7);
        gload16(xb + row * 64 + g * 4, &xs[(w * 16 + j * 4) * 64]);
    }
    asm volatile("s_waitcnt vmcnt(0)" ::: "memory");     // own 4 KB landed (per-wave, no barrier)

    // ---- own-quarter read (mt = w): 16 values/lane, no accumulation
    const int s = r & 7;                                 // XOR key: (mt*16+r)&7 == r&7
    float ps[16];
    #pragma unroll
    for (int kb = 0; kb < 2; ++kb) {
        const float* base = &xs[(w * 16 + r) * 64 + kb * 32];
        float4 v0 = *(const float4*)(base + (((q * 2 + 0) ^ s) << 2));
        float4 v1 = *(const float4*)(base + (((q * 2 + 1) ^ s) << 2));
        ps[kb*8+0] = v0.x; ps[kb*8+1] = v0.y; ps[kb*8+2] = v0.z; ps[kb*8+3] = v0.w;
        ps[kb*8+4] = v1.x; ps[kb*8+5] = v1.y; ps[kb*8+6] = v1.z; ps[kb*8+7] = v1.w;
    }

    // ---- router partial for this wave's 16 patches (fp32; same FMA structure as before)
    #pragma unroll
    for (int e2 = 0; e2 < 8; ++e2) {
        const float* rwe = rw + e2 * KK;
        float4 a0 = *(const float4*)(rwe + q * 8);
        float4 a1 = *(const float4*)(rwe + q * 8 + 4);
        float4 b0 = *(const float4*)(rwe + 32 + q * 8);
        float4 b1 = *(const float4*)(rwe + 32 + q * 8 + 4);
        float t = ps[0]*a0.x + ps[1]*a0.y + ps[2]*a0.z + ps[3]*a0.w
                + ps[4]*a1.x + ps[5]*a1.y + ps[6]*a1.z + ps[7]*a1.w
                + ps[8]*b0.x + ps[9]*b0.y + ps[10]*b0.z + ps[11]*b0.w
                + ps[12]*b1.x + ps[13]*b1.y + ps[14]*b1.z + ps[15]*b1.w;
        t += __shfl_xor(t, 1);  t += __shfl_xor(t, 2);  t += __shfl_xor(t, 4);
        t += __shfl_xor(t, 8);  t += __shfl_xor(t, 16); t += __shfl_xor(t, 32);
        if (lane == 0) sh_d[w][e2] = t;
    }
    __syncthreads();                                     // all quarters staged + all partials visible

    // ---- merge router partials in FIXED order -> bit-identical d/e/gate across waves
    float d[8];
    #pragma unroll
    for (int e2 = 0; e2 < 8; ++e2)
        d[e2] = ((sh_d[0][e2] + sh_d[1][e2]) + sh_d[2][e2]) + sh_d[3][e2];
    float gate = d[0]; int e = 0;
    #pragma unroll
    for (int e2 = 1; e2 < 8; ++e2)
        if (d[e2] > gate) { gate = d[e2]; e = e2; }

    // ---- select0 + loss adds (RELAXED atomics, spread over 32 copies), off the critical path
    if (w == 0 && lane < 8) {
        float on = (gate != 0.f) ? 1.f : 0.f;
        out[BB * 2 + b * 8 + lane] = (lane == e) ? on : 0.f;   // select0 (one-hot row)
        atomicAdd(&g_sum[b & (NGRP - 1)][lane], d[lane]);      // sum_b select[b,e]
        if (lane == e) atomicAdd(&g_sum[b & (NGRP - 1)][8 + lane], 1.f);
    }

    // ---- full-row A-frags from LDS (independent of expert; overlaps weight-load latency)
    short8 af[8];                                        // [mt*2+kb]
    #pragma unroll
    for (int mt = 0; mt < 4; ++mt) {
        #pragma unroll
        for (int kb = 0; kb < 2; ++kb) {
            const float* base = &xs[(mt * 16 + r) * 64 + kb * 32];
            float4 v0 = *(const float4*)(base + (((q * 2 + 0) ^ s) << 2));
            float4 v1 = *(const float4*)(base + (((q * 2 + 1) ^ s) << 2));
            uint4 u;
            u.x = pack2_trunc(v0.x, v0.y); u.y = pack2_trunc(v0.z, v0.w);
            u.z = pack2_trunc(v1.x, v1.y); u.w = pack2_trunc(v1.z, v1.w);
            af[mt * 2 + kb] = __builtin_bit_cast(short8, u);
        }
    }

    // ---- expert compute (this wave's 32 channels): inline fp32->bf16 B-frags, mfma, (z+bias)^3
    const float* we = ew + (size_t)e * (C2 * KK);
    float h = 0.f;
    #pragma unroll
    for (int ntl = 0; ntl < 2; ++ntl) {
        const int nt = w * 2 + ntl;
        float bs = eb[e * C2 + nt * 16 + r];             // c = nt*16 + (lane&15)
        const float* wr = we + (nt * 16 + r) * KK + q * 8;
        float4 w0 = *(const float4*)wr;
        float4 w1 = *(const float4*)(wr + 4);
        float4 w2 = *(const float4*)(wr + 32);
        float4 w3 = *(const float4*)(wr + 36);
        uint4 u0, u1;
        u0.x = pack2_trunc(w0.x, w0.y); u0.y = pack2_trunc(w0.z, w0.w);
        u0.z = pack2_trunc(w1.x, w1.y); u0.w = pack2_trunc(w1.z, w1.w);
        u1.x = pack2_trunc(w2.x, w2.y); u1.y = pack2_trunc(w2.z, w2.w);
        u1.z = pack2_trunc(w3.x, w3.y); u1.w = pack2_trunc(w3.z, w3.w);
        short8 bf0 = __builtin_bit_cast(short8, u0);
        short8 bf1 = __builtin_bit_cast(short8, u1);
        #pragma unroll
        for (int mt = 0; mt < 4; ++mt) {
            floatx4 a4 = (floatx4){0.f, 0.f, 0.f, 0.f};
            a4 = __builtin_amdgcn_mfma_f32_16x16x32_bf16(af[mt*2+0], bf0, a4, 0, 0, 0);
            a4 = __builtin_amdgcn_mfma_f32_16x16x32_bf16(af[mt*2+1], bf1, a4, 0, 0, 0);
            #pragma unroll
            for (int i = 0; i < 4; ++i) {
                float z = a4[i] + bs;
                h = fmaf(z * z, z, h);
            }
        }
    }
    #pragma unroll
    for (int off = 1; off < 64; off <<= 1)
        h += __shfl_xor(h, off);

    if (lane == 0) sh_h[w] = h;
    __syncthreads();

    if (threadIdx.x == 0) {
        float l0 = gate * (sh_h[0] + sh_h[1]);           // channels 0..63
        float l1 = gate * (sh_h[2] + sh_h[3]);           // channels 64..127
        float m = fmaxf(l0, l1);
        float e0 = __expf(l0 - m), e1 = __expf(l1 - m);
        float inv = 1.f / (e0 + e1);
        float2 o; o.x = e0 * inv; o.y = e1 * inv;
        *(float2*)(out + b * 2) = o;
    }
}

// Stage 2 (slim): reduce 32 accumulator copies (512 floats), write loss, reset copies.
__global__ __launch_bounds__(256) void loss2(float* __restrict__ out)
{
    __shared__ float red[16][16];                        // [copy-pair k][slot j]
    __shared__ float m[16];
    const int t = threadIdx.x;
    const int j = t & 15, k = t >> 4;                    // k in 0..15 covers copies k and k+16

    float v = g_sum[k][j] + g_sum[k + 16][j];
    red[k][j] = v;
    __syncthreads();

    // reset for next iteration (reads above are done; kernel boundary publishes to next moe)
    g_sum[k][j] = 0.f;
    g_sum[k + 16][j] = 0.f;

    if (t < 16) {
        float sv = 0.f;
        #pragma unroll
        for (int kk = 0; kk < 16; ++kk) sv += red[kk][t];
        m[t] = sv;
    }
    __syncthreads();
    if (t == 0) {
        float loss = 0.f;
        #pragma unroll
        for (int e2 = 0; e2 < 8; ++e2)
            loss += (m[e2] * (1.f / BB)) * (m[8 + e2] * (1.f / BB));
        out[BB * 2 + BB * 8] = loss * (float)EE;
    }
}

extern "C" void kernel_launch(void* const* d_in, const int* in_sizes, int n_in,
                              void* d_out, int out_size, void* d_ws, size_t ws_size,
                              hipStream_t stream) {
    (void)in_sizes; (void)n_in; (void)out_size; (void)d_ws; (void)ws_size;
    const float* x  = (const float*)d_in[0];
    const float* rw = (const float*)d_in[1];
    const float* ew = (const float*)d_in[2];
    const float* eb = (const float*)d_in[3];
    float* out = (float*)d_out;

    moe_main<<<NBLK, 256, 0, stream>>>(x, rw, ew, eb, out);
    loss2<<<1, 256, 0, stream>>>(out);
}